// Round 15
// baseline (264.035 us; speedup 1.0000x reference)
//
#include <hip/hip_runtime.h>
#include <stdint.h>

typedef __bf16 bf16;
typedef __bf16 bf16x4 __attribute__((ext_vector_type(4)));
typedef __bf16 bf16x8 __attribute__((ext_vector_type(8)));
typedef float  f32x4  __attribute__((ext_vector_type(4)));

#define DIM   768
#define HEADS 12
#define HD    64
#define SEQ   4096
#define NKT2  12   // 768 / BK64

// ---- async global->LDS, 16B per lane ----
__device__ __forceinline__ void gload16(const void* g, void* l) {
  typedef const __attribute__((address_space(1))) uint32_t* gp_t;
  typedef __attribute__((address_space(3))) uint32_t* lp_t;
  gp_t gp = reinterpret_cast<gp_t>(reinterpret_cast<uintptr_t>(g));
  lp_t lp = reinterpret_cast<lp_t>(reinterpret_cast<uintptr_t>(l));
  __builtin_amdgcn_global_load_lds(gp, lp, 16, 0, 0);
}

// ---- weight fp32 -> bf16 convert (both weights, one launch; 2304 blocks) ----
__global__ __launch_bounds__(256) void wcvt_kernel(const float* __restrict__ wq,
    const float* __restrict__ wp, bf16* __restrict__ dq, bf16* __restrict__ dp) {
  long i = (long)(blockIdx.x * 256 + threadIdx.x) * 4;
  const long NQ = 3L * DIM * DIM;
  const float* src; bf16* dst; long off;
  if (i < NQ) { src = wq; dst = dq; off = i; }
  else        { src = wp; dst = dp; off = i - NQ; }
  float4 v = *reinterpret_cast<const float4*>(src + off);
  bf16x4 o;
  o[0] = (bf16)v.x; o[1] = (bf16)v.y; o[2] = (bf16)v.z; o[3] = (bf16)v.w;
  *reinterpret_cast<bf16x4*>(dst + off) = o;
}

// ---- LayerNorm: one wave per row, fp32 stats, bf16 out ----
__global__ __launch_bounds__(256) void ln_kernel(const float* __restrict__ x,
    const float* __restrict__ gam, const float* __restrict__ bet,
    bf16* __restrict__ y) {
  const int tid = threadIdx.x, w = tid >> 6, l = tid & 63;
  const int row = blockIdx.x * 4 + w;
  const float* xr = x + (long)row * DIM;
  float4 v[3];
  float s = 0.f, ss = 0.f;
#pragma unroll
  for (int j = 0; j < 3; j++) {
    v[j] = *reinterpret_cast<const float4*>(xr + l * 4 + j * 256);
    s  += v[j].x + v[j].y + v[j].z + v[j].w;
    ss += v[j].x * v[j].x + v[j].y * v[j].y + v[j].z * v[j].z + v[j].w * v[j].w;
  }
#pragma unroll
  for (int m = 1; m < 64; m <<= 1) { s += __shfl_xor(s, m); ss += __shfl_xor(ss, m); }
  const float mu = s * (1.f / 768.f);
  const float rstd = rsqrtf(ss * (1.f / 768.f) - mu * mu + 1e-5f);
  bf16* yr = y + (long)row * DIM;
#pragma unroll
  for (int j = 0; j < 3; j++) {
    int c = l * 4 + j * 256;
    float4 g4 = *reinterpret_cast<const float4*>(gam + c);
    float4 b4 = *reinterpret_cast<const float4*>(bet + c);
    bf16x4 o;
    o[0] = (bf16)((v[j].x - mu) * rstd * g4.x + b4.x);
    o[1] = (bf16)((v[j].y - mu) * rstd * g4.y + b4.y);
    o[2] = (bf16)((v[j].z - mu) * rstd * g4.z + b4.z);
    o[3] = (bf16)((v[j].w - mu) * rstd * g4.w + b4.w);
    *reinterpret_cast<bf16x4*>(yr + c) = o;
  }
}

// ---- 128x128 bf16 MFMA GEMM, C = A[M,768] * Bw[N,768]^T ----
// Round-14 structure; changes: __launch_bounds__(512,8) -> 4 blocks/CU
// (32 waves/CU, HW max) + register diet (pA1/pB1 folded into immediate
// offsets: row+64 has identical swizzle phase). Requires <=64 regs/lane.
// MODE 0: q -> [bh][n][d]; k,v -> [bh][d][n] via [col][tok] LDS stage.
// MODE 1: proj (+bias, fp32 out [t][768]), NT=6
template <int MODE>
__global__ __launch_bounds__(512, 8) void gemm_kernel(
    const bf16* __restrict__ A, const bf16* __restrict__ Bw,
    bf16* __restrict__ qb, bf16* __restrict__ kb, bf16* __restrict__ vb,
    float* __restrict__ outp, const float* __restrict__ bias) {
  // staging: [A 128x64 | B 128x64] bf16 = 32KB; epilogue reuses as 32KB Cs
  __shared__ __align__(16) char lds[32768];
  const int tid = threadIdx.x;
  const int wid = tid >> 6, l = tid & 63;
  const int wr = wid >> 2, wc = wid & 3;      // 2M x 4N wave grid (64x32 each)
  const int l16 = l & 15, l4 = l >> 4;

  const int NT = (MODE == 0) ? 18 : 6;
  const int nwg = NT * 256;                    // 256 M-tiles (BM=128)
  const int orig = blockIdx.x;
  const int wgid = (orig & 7) * (nwg >> 3) + (orig >> 3);  // T1 bijective
  const int mt = wgid / NT, nt = wgid % NT;

  // staging sources (rows 128B; slot = byte[6:4] swizzled by row&7).
  // Second chunk (rows 64..127) = first chunk + 64*DIM (same swizzle phase).
  const int L0 = tid * 16;
  const int r0 = L0 >> 7, s0 = (L0 >> 4) & 7;
  const bf16* pA0 = A + (long)(mt * 128 + r0) * DIM + (s0 ^ (r0 & 7)) * 8;
  const bf16* pB0 = Bw + (long)(nt * 128 + r0) * DIM + (s0 ^ (r0 & 7)) * 8;

  // fragment LDS byte offsets (swizzled)
  int offA[2][4], offB[2][2];
#pragma unroll
  for (int ks = 0; ks < 2; ks++) {
#pragma unroll
    for (int mi = 0; mi < 4; mi++) {
      int row = wr * 64 + mi * 16 + l16;
      offA[ks][mi] = row * 128 + (((l4 + 4 * ks) ^ (row & 7)) << 4);
    }
#pragma unroll
    for (int ni = 0; ni < 2; ni++) {
      int row = wc * 32 + ni * 16 + l16;
      offB[ks][ni] = 16384 + row * 128 + (((l4 + 4 * ks) ^ (row & 7)) << 4);
    }
  }

  f32x4 acc[4][2];
#pragma unroll
  for (int m = 0; m < 4; m++)
#pragma unroll
    for (int n = 0; n < 2; n++) { f32x4 z4 = {0.f, 0.f, 0.f, 0.f}; acc[m][n] = z4; }

  for (int t = 0; t < NKT2; t++) {
    __syncthreads();
    gload16(pA0 + t * 64, lds + L0);
    gload16(pA0 + 64 * DIM + t * 64, lds + 8192 + L0);
    gload16(pB0 + t * 64, lds + 16384 + L0);
    gload16(pB0 + 64 * DIM + t * 64, lds + 24576 + L0);
    __syncthreads();
#pragma unroll
    for (int ks = 0; ks < 2; ks++) {
      bf16x8 a[4], b[2];
#pragma unroll
      for (int mi = 0; mi < 4; mi++)
        a[mi] = *reinterpret_cast<const bf16x8*>(lds + offA[ks][mi]);
#pragma unroll
      for (int ni = 0; ni < 2; ni++)
        b[ni] = *reinterpret_cast<const bf16x8*>(lds + offB[ks][ni]);
#pragma unroll
      for (int mi = 0; mi < 4; mi++)
#pragma unroll
        for (int ni = 0; ni < 2; ni++)
          acc[mi][ni] = __builtin_amdgcn_mfma_f32_16x16x32_bf16(a[mi], b[ni], acc[mi][ni], 0, 0, 0);
    }
  }

  if constexpr (MODE == 0) {
    const int s = nt / 6;   // 0=q, 1=k, 2=v (uniform per block)
    const int j = nt % 6;   // head pair
    if (s == 0) {
      // q: Cs[row][col] (row-major) -> coalesced [bh][n][d] scatter
      bf16* Cs = (bf16*)lds;
      __syncthreads();
#pragma unroll
      for (int mi = 0; mi < 4; mi++)
#pragma unroll
        for (int ni = 0; ni < 2; ni++)
#pragma unroll
          for (int i = 0; i < 4; i++) {
            float val = acc[mi][ni][i];
            val = val > 0.f ? val + 1.f : __expf(val);
            Cs[(wr * 64 + mi * 16 + l4 * 4 + i) * 128 + wc * 32 + ni * 16 + l16] = (bf16)val;
          }
      __syncthreads();
#pragma unroll
      for (int it = 0; it < 4; it++) {
        int bi = it * 8192 + tid * 16;
        int row = bi >> 8;
        int col = (bi & 255) >> 1;
        int h = j * 2 + (col >> 6), d = col & 63;
        int trow = mt * 128 + row;
        int bb = trow >> 12, tok = trow & 4095;
        *reinterpret_cast<bf16x8*>(qb +
            ((long)(bb * HEADS + h) * SEQ + tok) * HD + d) =
            *reinterpret_cast<const bf16x8*>(Cs + (bi >> 1));
      }
    } else {
      // k (elu+1) / v: [col][tok] LDS stage, both sides vectorized.
      // element (col, tok) at byte col*256 + ((tok*2) ^ ((col&7)<<4)).
      bf16* dst0 = (s == 1) ? kb : vb;
      __syncthreads();
#pragma unroll
      for (int mi = 0; mi < 4; mi++)
#pragma unroll
        for (int ni = 0; ni < 2; ni++) {
          int col = wc * 32 + ni * 16 + l16;
          int tok0 = wr * 64 + mi * 16 + l4 * 4;
          bf16x4 o;
#pragma unroll
          for (int i = 0; i < 4; i++) {
            float val = acc[mi][ni][i];
            if (s == 1) val = val > 0.f ? val + 1.f : __expf(val);
            o[i] = (bf16)val;
          }
          *reinterpret_cast<bf16x4*>(lds + col * 256 + ((tok0 * 2) ^ ((col & 7) << 4))) = o;
        }
      __syncthreads();
      const int bb = (mt * 128) >> 12;
      const int tokbase = (mt * 128) & 4095;
#pragma unroll
      for (int p = 0; p < 4; p++) {
        int col = p * 32 + (tid >> 4);      // 32 cols/pass, 16 lanes per col
        int tok = (tid & 15) * 8;           // 16B run along tok
        int h = j * 2 + (col >> 6), d = col & 63;
        bf16x8 o8 = *reinterpret_cast<const bf16x8*>(
            lds + col * 256 + ((tok * 2) ^ ((col & 7) << 4)));
        *reinterpret_cast<bf16x8*>(dst0 +
            ((long)(bb * HEADS + h) * HD + d) * SEQ + tokbase + tok) = o8;
      }
    }
  } else {
#pragma unroll
    for (int ni = 0; ni < 2; ni++) {
      int col = nt * 128 + wc * 32 + ni * 16 + l16;
      float bv = bias[col];
#pragma unroll
      for (int mi = 0; mi < 4; mi++)
#pragma unroll
        for (int i = 0; i < 4; i++) {
          long trow = mt * 128 + wr * 64 + mi * 16 + l4 * 4 + i;
          outp[trow * DIM + col] = acc[mi][ni][i] + bv;
        }
    }
  }
}

// ---- kv partials via MFMA: per (head, sp): kv[64][64] += KT·VT^T over 512 toks
__global__ __launch_bounds__(256) void kv_kernel(
    const bf16* __restrict__ ktb, const bf16* __restrict__ vtb,
    float* __restrict__ kv_part, float* __restrict__ ks_part) {
  __shared__ __align__(16) char lds[32768];
  const int head = blockIdx.x, sp = blockIdx.y;
  const int tid = threadIdx.x;
  const int wid = tid >> 6, l = tid & 63;
  const int wd = wid >> 1, we = wid & 1;
  const int l16 = l & 15, l4 = l >> 4;

  int offK[4][2], offV[4][2];
#pragma unroll
  for (int ks = 0; ks < 4; ks++) {
#pragma unroll
    for (int mi = 0; mi < 2; mi++) {
      int row = wd * 32 + mi * 16 + l16;
      offK[ks][mi] = row * 256 + ((ks * 64 + l4 * 16) ^ ((row & 7) << 4));
    }
#pragma unroll
    for (int ni = 0; ni < 2; ni++) {
      int row = we * 32 + ni * 16 + l16;
      offV[ks][ni] = 16384 + row * 256 + ((ks * 64 + l4 * 16) ^ ((row & 7) << 4));
    }
  }
  const bf16* srcK[4]; const bf16* srcV[4]; int ldst[4];
#pragma unroll
  for (int g = 0; g < 4; g++) {
    int L = g * 4096 + tid * 16;
    int r = L >> 8, cb = L & 255;
    int ce = (cb ^ ((r & 7) << 4)) >> 1;
    srcK[g] = ktb + ((long)head * HD + r) * SEQ + sp * 512 + ce;
    srcV[g] = vtb + ((long)head * HD + r) * SEQ + sp * 512 + ce;
    ldst[g] = L;
  }

  f32x4 acc[2][2];
#pragma unroll
  for (int m = 0; m < 2; m++)
#pragma unroll
    for (int n = 0; n < 2; n++) { f32x4 z4 = {0.f, 0.f, 0.f, 0.f}; acc[m][n] = z4; }
  float ksf = 0.f;
  const int ksd = tid >> 2, ksq = tid & 3;

  for (int c = 0; c < 4; c++) {
    __syncthreads();
#pragma unroll
    for (int g = 0; g < 4; g++) {
      gload16(srcK[g] + c * 128, lds + ldst[g]);
      gload16(srcV[g] + c * 128, lds + 16384 + ldst[g]);
    }
    __syncthreads();
#pragma unroll
    for (int q = 0; q < 4; q++) {
      bf16x8 k8 = *reinterpret_cast<const bf16x8*>(
          lds + ksd * 256 + ((ksq * 64 + q * 16) ^ ((ksd & 7) << 4)));
#pragma unroll
      for (int jj = 0; jj < 8; jj++) ksf += (float)k8[jj];
    }
#pragma unroll
    for (int ks = 0; ks < 4; ks++) {
      bf16x8 a[2], b[2];
      a[0] = *reinterpret_cast<const bf16x8*>(lds + offK[ks][0]);
      a[1] = *reinterpret_cast<const bf16x8*>(lds + offK[ks][1]);
      b[0] = *reinterpret_cast<const bf16x8*>(lds + offV[ks][0]);
      b[1] = *reinterpret_cast<const bf16x8*>(lds + offV[ks][1]);
#pragma unroll
      for (int mi = 0; mi < 2; mi++)
#pragma unroll
        for (int ni = 0; ni < 2; ni++)
          acc[mi][ni] = __builtin_amdgcn_mfma_f32_16x16x32_bf16(a[mi], b[ni], acc[mi][ni], 0, 0, 0);
    }
  }
  ksf += __shfl_xor(ksf, 1);
  ksf += __shfl_xor(ksf, 2);
  if (ksq == 0) ks_part[(head * 8 + sp) * 64 + ksd] = ksf;

  __syncthreads();
#pragma unroll
  for (int mi = 0; mi < 2; mi++)
#pragma unroll
    for (int ni = 0; ni < 2; ni++)
#pragma unroll
      for (int i = 0; i < 4; i++) {
        int dd = wd * 32 + mi * 16 + l4 * 4 + i;
        int ee = we * 32 + ni * 16 + l16;
        *reinterpret_cast<float*>(lds + dd * 256 + ((ee * 4) ^ ((dd & 7) << 4))) = acc[mi][ni][i];
      }
  __syncthreads();
  float* dst = kv_part + (long)(head * 8 + sp) * 4096;
  const int dd2 = tid >> 2, eq = tid & 3;
#pragma unroll
  for (int q = 0; q < 4; q++) {
    f32x4 v4 = *reinterpret_cast<const f32x4*>(
        lds + dd2 * 256 + ((eq * 64 + q * 16) ^ ((dd2 & 7) << 4)));
    *reinterpret_cast<f32x4*>(dst + dd2 * 64 + eq * 16 + q * 4) = v4;
  }
}

// ---- finalize: sum partials -> kvT bf16 [head][e][d], ksum fp32 [head][d] ----
__global__ __launch_bounds__(256) void kvfin_kernel(const float* __restrict__ kv_part,
    const float* __restrict__ ks_part, bf16* __restrict__ kvT, float* __restrict__ ksum) {
  const int head = blockIdx.x, tid = threadIdx.x;
  const long base = (long)head * 8 * 4096;
  const int d = tid >> 2, ecol = (tid & 3) * 16;
  float s[16];
#pragma unroll
  for (int q = 0; q < 16; q++) s[q] = 0.f;
  for (int sp = 0; sp < 8; sp++) {
    const float* p = kv_part + base + sp * 4096 + d * 64 + ecol;
#pragma unroll
    for (int q = 0; q < 16; q++) s[q] += p[q];
  }
#pragma unroll
  for (int q = 0; q < 16; q++) kvT[head * 4096 + (ecol + q) * 64 + d] = (bf16)s[q];
  if (tid < 64) {
    float t = 0.f;
    for (int sp = 0; sp < 8; sp++) t += ks_part[(head * 8 + sp) * 64 + tid];
    ksum[head * 64 + tid] = t;
  }
}

// ---- out_pre = (Q @ kv) * z, bf16 out in [t][768] layout ----
__global__ __launch_bounds__(256) void qout_kernel(const bf16* __restrict__ qb,
    const bf16* __restrict__ kvT, const float* __restrict__ ksum,
    bf16* __restrict__ outp) {
  __shared__ __align__(16) bf16 Qs[128 * 64];
  __shared__ __align__(16) bf16 Bs2[64 * 64];
  __shared__ float ksum_s[64];
  __shared__ float z_s[128];
  const int head = blockIdx.x, tt = blockIdx.y;
  const int b = head / HEADS, h = head % HEADS;
  const int tid = threadIdx.x, w = tid >> 6, l = tid & 63;
  const int l16 = l & 15, l4 = l >> 4;
  const bf16* Qg = qb + (long)(head * SEQ + tt * 128) * HD;
#pragma unroll
  for (int r = 0; r < 4; r++) gload16(Qg + r * 2048 + tid * 8, Qs + r * 2048 + tid * 8);
#pragma unroll
  for (int r = 0; r < 2; r++)
    gload16(kvT + head * 4096 + r * 2048 + tid * 8, Bs2 + r * 2048 + tid * 8);
  if (tid < 64) ksum_s[tid] = ksum[head * 64 + tid];
  __syncthreads();
  {
    const int tok = tid >> 1, hf = tid & 1;
    float dsum = 0.f;
#pragma unroll
    for (int q = 0; q < 4; q++) {
      bf16x8 q8 = *reinterpret_cast<const bf16x8*>(Qs + tok * 64 + hf * 32 + q * 8);
#pragma unroll
      for (int jj = 0; jj < 8; jj++) dsum += (float)q8[jj] * ksum_s[hf * 32 + q * 8 + jj];
    }
    dsum += __shfl_xor(dsum, 1);
    if (hf == 0) z_s[tok] = 1.f / (dsum + 1e-6f);
  }
  f32x4 acc[2][4];
#pragma unroll
  for (int m = 0; m < 2; m++)
#pragma unroll
    for (int n = 0; n < 4; n++) { f32x4 z4 = {0.f, 0.f, 0.f, 0.f}; acc[m][n] = z4; }
#pragma unroll
  for (int kk = 0; kk < 2; kk++) {
    bf16x8 af[2], bfr[4];
#pragma unroll
    for (int m = 0; m < 2; m++)
      af[m] = *reinterpret_cast<const bf16x8*>(Qs + (w * 32 + m * 16 + l16) * 64 + kk * 32 + l4 * 8);
#pragma unroll
    for (int n = 0; n < 4; n++)
      bfr[n] = *reinterpret_cast<const bf16x8*>(Bs2 + (n * 16 + l16) * 64 + kk * 32 + l4 * 8);
#pragma unroll
    for (int m = 0; m < 2; m++)
#pragma unroll
      for (int n = 0; n < 4; n++)
        acc[m][n] = __builtin_amdgcn_mfma_f32_16x16x32_bf16(af[m], bfr[n], acc[m][n], 0, 0, 0);
  }
  __syncthreads();
#pragma unroll
  for (int m = 0; m < 2; m++)
#pragma unroll
    for (int n = 0; n < 4; n++)
#pragma unroll
      for (int i = 0; i < 4; i++) {
        int row = w * 32 + m * 16 + l4 * 4 + i;
        Qs[row * 64 + n * 16 + l16] = (bf16)(acc[m][n][i] * z_s[row]);
      }
  __syncthreads();
#pragma unroll
  for (int r = 0; r < 4; r++) {
    int idx = r * 2048 + tid * 8;
    int row = idx >> 6, col = idx & 63;
    *reinterpret_cast<bf16x8*>(outp + (long)(b * SEQ + tt * 128 + row) * DIM + h * HD + col) =
        *reinterpret_cast<const bf16x8*>(Qs + idx);
  }
}

extern "C" void kernel_launch(void* const* d_in, const int* in_sizes, int n_in,
                              void* d_out, int out_size, void* d_ws, size_t ws_size,
                              hipStream_t stream) {
  const float* x     = (const float*)d_in[0];
  const float* gam   = (const float*)d_in[1];
  const float* bet   = (const float*)d_in[2];
  const float* wqkv  = (const float*)d_in[3];
  const float* wproj = (const float*)d_in[4];
  const float* bproj = (const float*)d_in[5];
  float* out = (float*)d_out;
  char* ws = (char*)d_ws;

  bf16*  y       = (bf16*)(ws);                    // 50331648 B (reused as out_pre)
  bf16*  qb      = (bf16*)(ws + 50331648);         // 50331648 B  [bh][n][d]
  bf16*  kb      = (bf16*)(ws + 100663296);        // 50331648 B  [bh][d][n] (kT)
  bf16*  vb      = (bf16*)(ws + 150994944);        // 50331648 B  [bh][d][n] (vT)
  bf16*  wqkv_b  = (bf16*)(ws + 201326592);        // 3538944 B
  bf16*  wproj_b = (bf16*)(ws + 204865536);        // 1179648 B
  float* kv_part = (float*)(ws + 206045184);       // 12582912 B
  float* ks_part = (float*)(ws + 218628096);       // 196608 B
  bf16*  kvT     = (bf16*)(ws + 218824704);        // 786432 B
  float* ksum    = (float*)(ws + 219611136);       // 24576 B

  wcvt_kernel<<<2304, 256, 0, stream>>>(wqkv, wproj, wqkv_b, wproj_b);
  ln_kernel<<<8192, 256, 0, stream>>>(x, gam, bet, y);
  gemm_kernel<0><<<dim3(18 * 256), 512, 0, stream>>>(y, wqkv_b, qb, kb, vb, nullptr, nullptr);
  kv_kernel<<<dim3(96, 8), 256, 0, stream>>>(kb, vb, kv_part, ks_part);
  kvfin_kernel<<<96, 256, 0, stream>>>(kv_part, ks_part, kvT, ksum);
  qout_kernel<<<dim3(96, 32), 256, 0, stream>>>(qb, kvT, ksum, y);
  gemm_kernel<1><<<dim3(6 * 256), 512, 0, stream>>>(y, wproj_b, nullptr, nullptr, nullptr, out, bproj);
}

// Round 16
// 242.407 us; speedup vs baseline: 1.0892x; 1.0892x over previous
//
#include <hip/hip_runtime.h>
#include <stdint.h>

typedef __bf16 bf16;
typedef __bf16 bf16x4 __attribute__((ext_vector_type(4)));
typedef __bf16 bf16x8 __attribute__((ext_vector_type(8)));
typedef float  f32x4  __attribute__((ext_vector_type(4)));

#define DIM   768
#define HEADS 12
#define HD    64
#define SEQ   4096
#define NKT2  12   // 768 / BK64

// ---- async global->LDS, 16B per lane ----
__device__ __forceinline__ void gload16(const void* g, void* l) {
  typedef const __attribute__((address_space(1))) uint32_t* gp_t;
  typedef __attribute__((address_space(3))) uint32_t* lp_t;
  gp_t gp = reinterpret_cast<gp_t>(reinterpret_cast<uintptr_t>(g));
  lp_t lp = reinterpret_cast<lp_t>(reinterpret_cast<uintptr_t>(l));
  __builtin_amdgcn_global_load_lds(gp, lp, 16, 0, 0);
}

// ---- weight fp32 -> bf16 convert (both weights, one launch; 2304 blocks) ----
__global__ __launch_bounds__(256) void wcvt_kernel(const float* __restrict__ wq,
    const float* __restrict__ wp, bf16* __restrict__ dq, bf16* __restrict__ dp) {
  long i = (long)(blockIdx.x * 256 + threadIdx.x) * 4;
  const long NQ = 3L * DIM * DIM;
  const float* src; bf16* dst; long off;
  if (i < NQ) { src = wq; dst = dq; off = i; }
  else        { src = wp; dst = dp; off = i - NQ; }
  float4 v = *reinterpret_cast<const float4*>(src + off);
  bf16x4 o;
  o[0] = (bf16)v.x; o[1] = (bf16)v.y; o[2] = (bf16)v.z; o[3] = (bf16)v.w;
  *reinterpret_cast<bf16x4*>(dst + off) = o;
}

// ---- LayerNorm: one wave per row, fp32 stats, bf16 out ----
__global__ __launch_bounds__(256) void ln_kernel(const float* __restrict__ x,
    const float* __restrict__ gam, const float* __restrict__ bet,
    bf16* __restrict__ y) {
  const int tid = threadIdx.x, w = tid >> 6, l = tid & 63;
  const int row = blockIdx.x * 4 + w;
  const float* xr = x + (long)row * DIM;
  float4 v[3];
  float s = 0.f, ss = 0.f;
#pragma unroll
  for (int j = 0; j < 3; j++) {
    v[j] = *reinterpret_cast<const float4*>(xr + l * 4 + j * 256);
    s  += v[j].x + v[j].y + v[j].z + v[j].w;
    ss += v[j].x * v[j].x + v[j].y * v[j].y + v[j].z * v[j].z + v[j].w * v[j].w;
  }
#pragma unroll
  for (int m = 1; m < 64; m <<= 1) { s += __shfl_xor(s, m); ss += __shfl_xor(ss, m); }
  const float mu = s * (1.f / 768.f);
  const float rstd = rsqrtf(ss * (1.f / 768.f) - mu * mu + 1e-5f);
  bf16* yr = y + (long)row * DIM;
#pragma unroll
  for (int j = 0; j < 3; j++) {
    int c = l * 4 + j * 256;
    float4 g4 = *reinterpret_cast<const float4*>(gam + c);
    float4 b4 = *reinterpret_cast<const float4*>(bet + c);
    bf16x4 o;
    o[0] = (bf16)((v[j].x - mu) * rstd * g4.x + b4.x);
    o[1] = (bf16)((v[j].y - mu) * rstd * g4.y + b4.y);
    o[2] = (bf16)((v[j].z - mu) * rstd * g4.z + b4.z);
    o[3] = (bf16)((v[j].w - mu) * rstd * g4.w + b4.w);
    *reinterpret_cast<bf16x4*>(yr + c) = o;
  }
}

// ---- 128x128 bf16 MFMA GEMM, C = A[M,768] * Bw[N,768]^T ----
// MINW per mode: MODE 0 -> 8 (4 blk/CU, reg diet OK: LDS-staged epilogue);
// MODE 1 -> 6 (3 blk/CU; fp32-store epilogue needs the extra regs).
// MODE 0: q -> [bh][n][d]; k,v -> [bh][d][n] via [col][tok] LDS stage.
// MODE 1: proj (+bias, fp32 out [t][768]), NT=6
template <int MODE, int MINW>
__global__ __launch_bounds__(512, MINW) void gemm_kernel(
    const bf16* __restrict__ A, const bf16* __restrict__ Bw,
    bf16* __restrict__ qb, bf16* __restrict__ kb, bf16* __restrict__ vb,
    float* __restrict__ outp, const float* __restrict__ bias) {
  // staging: [A 128x64 | B 128x64] bf16 = 32KB; epilogue reuses as 32KB Cs
  __shared__ __align__(16) char lds[32768];
  const int tid = threadIdx.x;
  const int wid = tid >> 6, l = tid & 63;
  const int wr = wid >> 2, wc = wid & 3;      // 2M x 4N wave grid (64x32 each)
  const int l16 = l & 15, l4 = l >> 4;

  const int NT = (MODE == 0) ? 18 : 6;
  const int nwg = NT * 256;                    // 256 M-tiles (BM=128)
  const int orig = blockIdx.x;
  const int wgid = (orig & 7) * (nwg >> 3) + (orig >> 3);  // T1 bijective
  const int mt = wgid / NT, nt = wgid % NT;

  // staging sources (rows 128B; slot = byte[6:4] swizzled by row&7).
  // Second chunk (rows 64..127) = first chunk + 64*DIM (same swizzle phase).
  const int L0 = tid * 16;
  const int r0 = L0 >> 7, s0 = (L0 >> 4) & 7;
  const bf16* pA0 = A + (long)(mt * 128 + r0) * DIM + (s0 ^ (r0 & 7)) * 8;
  const bf16* pB0 = Bw + (long)(nt * 128 + r0) * DIM + (s0 ^ (r0 & 7)) * 8;

  // fragment LDS byte offsets (swizzled)
  int offA[2][4], offB[2][2];
#pragma unroll
  for (int ks = 0; ks < 2; ks++) {
#pragma unroll
    for (int mi = 0; mi < 4; mi++) {
      int row = wr * 64 + mi * 16 + l16;
      offA[ks][mi] = row * 128 + (((l4 + 4 * ks) ^ (row & 7)) << 4);
    }
#pragma unroll
    for (int ni = 0; ni < 2; ni++) {
      int row = wc * 32 + ni * 16 + l16;
      offB[ks][ni] = 16384 + row * 128 + (((l4 + 4 * ks) ^ (row & 7)) << 4);
    }
  }

  f32x4 acc[4][2];
#pragma unroll
  for (int m = 0; m < 4; m++)
#pragma unroll
    for (int n = 0; n < 2; n++) { f32x4 z4 = {0.f, 0.f, 0.f, 0.f}; acc[m][n] = z4; }

  for (int t = 0; t < NKT2; t++) {
    __syncthreads();
    gload16(pA0 + t * 64, lds + L0);
    gload16(pA0 + 64 * DIM + t * 64, lds + 8192 + L0);
    gload16(pB0 + t * 64, lds + 16384 + L0);
    gload16(pB0 + 64 * DIM + t * 64, lds + 24576 + L0);
    __syncthreads();
#pragma unroll
    for (int ks = 0; ks < 2; ks++) {
      bf16x8 a[4], b[2];
#pragma unroll
      for (int mi = 0; mi < 4; mi++)
        a[mi] = *reinterpret_cast<const bf16x8*>(lds + offA[ks][mi]);
#pragma unroll
      for (int ni = 0; ni < 2; ni++)
        b[ni] = *reinterpret_cast<const bf16x8*>(lds + offB[ks][ni]);
#pragma unroll
      for (int mi = 0; mi < 4; mi++)
#pragma unroll
        for (int ni = 0; ni < 2; ni++)
          acc[mi][ni] = __builtin_amdgcn_mfma_f32_16x16x32_bf16(a[mi], b[ni], acc[mi][ni], 0, 0, 0);
    }
  }

  if constexpr (MODE == 0) {
    const int s = nt / 6;   // 0=q, 1=k, 2=v (uniform per block)
    const int j = nt % 6;   // head pair
    if (s == 0) {
      // q: Cs[row][col] (row-major) -> coalesced [bh][n][d] scatter
      bf16* Cs = (bf16*)lds;
      __syncthreads();
#pragma unroll
      for (int mi = 0; mi < 4; mi++)
#pragma unroll
        for (int ni = 0; ni < 2; ni++)
#pragma unroll
          for (int i = 0; i < 4; i++) {
            float val = acc[mi][ni][i];
            val = val > 0.f ? val + 1.f : __expf(val);
            Cs[(wr * 64 + mi * 16 + l4 * 4 + i) * 128 + wc * 32 + ni * 16 + l16] = (bf16)val;
          }
      __syncthreads();
#pragma unroll
      for (int it = 0; it < 4; it++) {
        int bi = it * 8192 + tid * 16;
        int row = bi >> 8;
        int col = (bi & 255) >> 1;
        int h = j * 2 + (col >> 6), d = col & 63;
        int trow = mt * 128 + row;
        int bb = trow >> 12, tok = trow & 4095;
        *reinterpret_cast<bf16x8*>(qb +
            ((long)(bb * HEADS + h) * SEQ + tok) * HD + d) =
            *reinterpret_cast<const bf16x8*>(Cs + (bi >> 1));
      }
    } else {
      // k (elu+1) / v: [col][tok] LDS stage, both sides vectorized.
      // element (col, tok) at byte col*256 + ((tok*2) ^ ((col&7)<<4)).
      bf16* dst0 = (s == 1) ? kb : vb;
      __syncthreads();
#pragma unroll
      for (int mi = 0; mi < 4; mi++)
#pragma unroll
        for (int ni = 0; ni < 2; ni++) {
          int col = wc * 32 + ni * 16 + l16;
          int tok0 = wr * 64 + mi * 16 + l4 * 4;
          bf16x4 o;
#pragma unroll
          for (int i = 0; i < 4; i++) {
            float val = acc[mi][ni][i];
            if (s == 1) val = val > 0.f ? val + 1.f : __expf(val);
            o[i] = (bf16)val;
          }
          *reinterpret_cast<bf16x4*>(lds + col * 256 + ((tok0 * 2) ^ ((col & 7) << 4))) = o;
        }
      __syncthreads();
      const int bb = (mt * 128) >> 12;
      const int tokbase = (mt * 128) & 4095;
#pragma unroll
      for (int p = 0; p < 4; p++) {
        int col = p * 32 + (tid >> 4);      // 32 cols/pass, 16 lanes per col
        int tok = (tid & 15) * 8;           // 16B run along tok
        int h = j * 2 + (col >> 6), d = col & 63;
        bf16x8 o8 = *reinterpret_cast<const bf16x8*>(
            lds + col * 256 + ((tok * 2) ^ ((col & 7) << 4)));
        *reinterpret_cast<bf16x8*>(dst0 +
            ((long)(bb * HEADS + h) * HD + d) * SEQ + tokbase + tok) = o8;
      }
    }
  } else {
#pragma unroll
    for (int ni = 0; ni < 2; ni++) {
      int col = nt * 128 + wc * 32 + ni * 16 + l16;
      float bv = bias[col];
#pragma unroll
      for (int mi = 0; mi < 4; mi++)
#pragma unroll
        for (int i = 0; i < 4; i++) {
          long trow = mt * 128 + wr * 64 + mi * 16 + l4 * 4 + i;
          outp[trow * DIM + col] = acc[mi][ni][i] + bv;
        }
    }
  }
}

// ---- kv partials via MFMA: per (head, sp): kv[64][64] += KT·VT^T over 512 toks
__global__ __launch_bounds__(256) void kv_kernel(
    const bf16* __restrict__ ktb, const bf16* __restrict__ vtb,
    float* __restrict__ kv_part, float* __restrict__ ks_part) {
  __shared__ __align__(16) char lds[32768];
  const int head = blockIdx.x, sp = blockIdx.y;
  const int tid = threadIdx.x;
  const int wid = tid >> 6, l = tid & 63;
  const int wd = wid >> 1, we = wid & 1;
  const int l16 = l & 15, l4 = l >> 4;

  int offK[4][2], offV[4][2];
#pragma unroll
  for (int ks = 0; ks < 4; ks++) {
#pragma unroll
    for (int mi = 0; mi < 2; mi++) {
      int row = wd * 32 + mi * 16 + l16;
      offK[ks][mi] = row * 256 + ((ks * 64 + l4 * 16) ^ ((row & 7) << 4));
    }
#pragma unroll
    for (int ni = 0; ni < 2; ni++) {
      int row = we * 32 + ni * 16 + l16;
      offV[ks][ni] = 16384 + row * 256 + ((ks * 64 + l4 * 16) ^ ((row & 7) << 4));
    }
  }
  const bf16* srcK[4]; const bf16* srcV[4]; int ldst[4];
#pragma unroll
  for (int g = 0; g < 4; g++) {
    int L = g * 4096 + tid * 16;
    int r = L >> 8, cb = L & 255;
    int ce = (cb ^ ((r & 7) << 4)) >> 1;
    srcK[g] = ktb + ((long)head * HD + r) * SEQ + sp * 512 + ce;
    srcV[g] = vtb + ((long)head * HD + r) * SEQ + sp * 512 + ce;
    ldst[g] = L;
  }

  f32x4 acc[2][2];
#pragma unroll
  for (int m = 0; m < 2; m++)
#pragma unroll
    for (int n = 0; n < 2; n++) { f32x4 z4 = {0.f, 0.f, 0.f, 0.f}; acc[m][n] = z4; }
  float ksf = 0.f;
  const int ksd = tid >> 2, ksq = tid & 3;

  for (int c = 0; c < 4; c++) {
    __syncthreads();
#pragma unroll
    for (int g = 0; g < 4; g++) {
      gload16(srcK[g] + c * 128, lds + ldst[g]);
      gload16(srcV[g] + c * 128, lds + 16384 + ldst[g]);
    }
    __syncthreads();
#pragma unroll
    for (int q = 0; q < 4; q++) {
      bf16x8 k8 = *reinterpret_cast<const bf16x8*>(
          lds + ksd * 256 + ((ksq * 64 + q * 16) ^ ((ksd & 7) << 4)));
#pragma unroll
      for (int jj = 0; jj < 8; jj++) ksf += (float)k8[jj];
    }
#pragma unroll
    for (int ks = 0; ks < 4; ks++) {
      bf16x8 a[2], b[2];
      a[0] = *reinterpret_cast<const bf16x8*>(lds + offK[ks][0]);
      a[1] = *reinterpret_cast<const bf16x8*>(lds + offK[ks][1]);
      b[0] = *reinterpret_cast<const bf16x8*>(lds + offV[ks][0]);
      b[1] = *reinterpret_cast<const bf16x8*>(lds + offV[ks][1]);
#pragma unroll
      for (int mi = 0; mi < 2; mi++)
#pragma unroll
        for (int ni = 0; ni < 2; ni++)
          acc[mi][ni] = __builtin_amdgcn_mfma_f32_16x16x32_bf16(a[mi], b[ni], acc[mi][ni], 0, 0, 0);
    }
  }
  ksf += __shfl_xor(ksf, 1);
  ksf += __shfl_xor(ksf, 2);
  if (ksq == 0) ks_part[(head * 8 + sp) * 64 + ksd] = ksf;

  __syncthreads();
#pragma unroll
  for (int mi = 0; mi < 2; mi++)
#pragma unroll
    for (int ni = 0; ni < 2; ni++)
#pragma unroll
      for (int i = 0; i < 4; i++) {
        int dd = wd * 32 + mi * 16 + l4 * 4 + i;
        int ee = we * 32 + ni * 16 + l16;
        *reinterpret_cast<float*>(lds + dd * 256 + ((ee * 4) ^ ((dd & 7) << 4))) = acc[mi][ni][i];
      }
  __syncthreads();
  float* dst = kv_part + (long)(head * 8 + sp) * 4096;
  const int dd2 = tid >> 2, eq = tid & 3;
#pragma unroll
  for (int q = 0; q < 4; q++) {
    f32x4 v4 = *reinterpret_cast<const f32x4*>(
        lds + dd2 * 256 + ((eq * 64 + q * 16) ^ ((dd2 & 7) << 4)));
    *reinterpret_cast<f32x4*>(dst + dd2 * 64 + eq * 16 + q * 4) = v4;
  }
}

// ---- finalize: sum partials -> kvT bf16 [head][e][d], ksum fp32 [head][d] ----
__global__ __launch_bounds__(256) void kvfin_kernel(const float* __restrict__ kv_part,
    const float* __restrict__ ks_part, bf16* __restrict__ kvT, float* __restrict__ ksum) {
  const int head = blockIdx.x, tid = threadIdx.x;
  const long base = (long)head * 8 * 4096;
  const int d = tid >> 2, ecol = (tid & 3) * 16;
  float s[16];
#pragma unroll
  for (int q = 0; q < 16; q++) s[q] = 0.f;
  for (int sp = 0; sp < 8; sp++) {
    const float* p = kv_part + base + sp * 4096 + d * 64 + ecol;
#pragma unroll
    for (int q = 0; q < 16; q++) s[q] += p[q];
  }
#pragma unroll
  for (int q = 0; q < 16; q++) kvT[head * 4096 + (ecol + q) * 64 + d] = (bf16)s[q];
  if (tid < 64) {
    float t = 0.f;
    for (int sp = 0; sp < 8; sp++) t += ks_part[(head * 8 + sp) * 64 + tid];
    ksum[head * 64 + tid] = t;
  }
}

// ---- out_pre = (Q @ kv) * z, bf16 out in [t][768] layout ----
__global__ __launch_bounds__(256) void qout_kernel(const bf16* __restrict__ qb,
    const bf16* __restrict__ kvT, const float* __restrict__ ksum,
    bf16* __restrict__ outp) {
  __shared__ __align__(16) bf16 Qs[128 * 64];
  __shared__ __align__(16) bf16 Bs2[64 * 64];
  __shared__ float ksum_s[64];
  __shared__ float z_s[128];
  const int head = blockIdx.x, tt = blockIdx.y;
  const int b = head / HEADS, h = head % HEADS;
  const int tid = threadIdx.x, w = tid >> 6, l = tid & 63;
  const int l16 = l & 15, l4 = l >> 4;
  const bf16* Qg = qb + (long)(head * SEQ + tt * 128) * HD;
#pragma unroll
  for (int r = 0; r < 4; r++) gload16(Qg + r * 2048 + tid * 8, Qs + r * 2048 + tid * 8);
#pragma unroll
  for (int r = 0; r < 2; r++)
    gload16(kvT + head * 4096 + r * 2048 + tid * 8, Bs2 + r * 2048 + tid * 8);
  if (tid < 64) ksum_s[tid] = ksum[head * 64 + tid];
  __syncthreads();
  {
    const int tok = tid >> 1, hf = tid & 1;
    float dsum = 0.f;
#pragma unroll
    for (int q = 0; q < 4; q++) {
      bf16x8 q8 = *reinterpret_cast<const bf16x8*>(Qs + tok * 64 + hf * 32 + q * 8);
#pragma unroll
      for (int jj = 0; jj < 8; jj++) dsum += (float)q8[jj] * ksum_s[hf * 32 + q * 8 + jj];
    }
    dsum += __shfl_xor(dsum, 1);
    if (hf == 0) z_s[tok] = 1.f / (dsum + 1e-6f);
  }
  f32x4 acc[2][4];
#pragma unroll
  for (int m = 0; m < 2; m++)
#pragma unroll
    for (int n = 0; n < 4; n++) { f32x4 z4 = {0.f, 0.f, 0.f, 0.f}; acc[m][n] = z4; }
#pragma unroll
  for (int kk = 0; kk < 2; kk++) {
    bf16x8 af[2], bfr[4];
#pragma unroll
    for (int m = 0; m < 2; m++)
      af[m] = *reinterpret_cast<const bf16x8*>(Qs + (w * 32 + m * 16 + l16) * 64 + kk * 32 + l4 * 8);
#pragma unroll
    for (int n = 0; n < 4; n++)
      bfr[n] = *reinterpret_cast<const bf16x8*>(Bs2 + (n * 16 + l16) * 64 + kk * 32 + l4 * 8);
#pragma unroll
    for (int m = 0; m < 2; m++)
#pragma unroll
      for (int n = 0; n < 4; n++)
        acc[m][n] = __builtin_amdgcn_mfma_f32_16x16x32_bf16(af[m], bfr[n], acc[m][n], 0, 0, 0);
  }
  __syncthreads();
#pragma unroll
  for (int m = 0; m < 2; m++)
#pragma unroll
    for (int n = 0; n < 4; n++)
#pragma unroll
      for (int i = 0; i < 4; i++) {
        int row = w * 32 + m * 16 + l4 * 4 + i;
        Qs[row * 64 + n * 16 + l16] = (bf16)(acc[m][n][i] * z_s[row]);
      }
  __syncthreads();
#pragma unroll
  for (int r = 0; r < 4; r++) {
    int idx = r * 2048 + tid * 8;
    int row = idx >> 6, col = idx & 63;
    *reinterpret_cast<bf16x8*>(outp + (long)(b * SEQ + tt * 128 + row) * DIM + h * HD + col) =
        *reinterpret_cast<const bf16x8*>(Qs + idx);
  }
}

extern "C" void kernel_launch(void* const* d_in, const int* in_sizes, int n_in,
                              void* d_out, int out_size, void* d_ws, size_t ws_size,
                              hipStream_t stream) {
  const float* x     = (const float*)d_in[0];
  const float* gam   = (const float*)d_in[1];
  const float* bet   = (const float*)d_in[2];
  const float* wqkv  = (const float*)d_in[3];
  const float* wproj = (const float*)d_in[4];
  const float* bproj = (const float*)d_in[5];
  float* out = (float*)d_out;
  char* ws = (char*)d_ws;

  bf16*  y       = (bf16*)(ws);                    // 50331648 B (reused as out_pre)
  bf16*  qb      = (bf16*)(ws + 50331648);         // 50331648 B  [bh][n][d]
  bf16*  kb      = (bf16*)(ws + 100663296);        // 50331648 B  [bh][d][n] (kT)
  bf16*  vb      = (bf16*)(ws + 150994944);        // 50331648 B  [bh][d][n] (vT)
  bf16*  wqkv_b  = (bf16*)(ws + 201326592);        // 3538944 B
  bf16*  wproj_b = (bf16*)(ws + 204865536);        // 1179648 B
  float* kv_part = (float*)(ws + 206045184);       // 12582912 B
  float* ks_part = (float*)(ws + 218628096);       // 196608 B
  bf16*  kvT     = (bf16*)(ws + 218824704);        // 786432 B
  float* ksum    = (float*)(ws + 219611136);       // 24576 B

  wcvt_kernel<<<2304, 256, 0, stream>>>(wqkv, wproj, wqkv_b, wproj_b);
  ln_kernel<<<8192, 256, 0, stream>>>(x, gam, bet, y);
  gemm_kernel<0, 8><<<dim3(18 * 256), 512, 0, stream>>>(y, wqkv_b, qb, kb, vb, nullptr, nullptr);
  kv_kernel<<<dim3(96, 8), 256, 0, stream>>>(kb, vb, kv_part, ks_part);
  kvfin_kernel<<<96, 256, 0, stream>>>(kv_part, ks_part, kvT, ksum);
  qout_kernel<<<dim3(96, 32), 256, 0, stream>>>(qb, kvT, ksum, y);
  gemm_kernel<1, 6><<<dim3(6 * 256), 512, 0, stream>>>(y, wproj_b, nullptr, nullptr, nullptr, out, bproj);
}